// Round 1
// baseline (214.774 us; speedup 1.0000x reference)
//
#include <hip/hip_runtime.h>
#include <cstdint>
#include <cstddef>

typedef __attribute__((ext_vector_type(8))) short short8v;
typedef __attribute__((ext_vector_type(4))) float f32x4;

__device__ __forceinline__ unsigned short f2bf(float f) {
  union { float f; uint32_t u; } v; v.f = f;
  uint32_t u = v.u;
  return (unsigned short)((u + 0x7fffu + ((u >> 16) & 1u)) >> 16);
}

__device__ __forceinline__ void load_lds_16B(const void* g, void* l) {
  __builtin_amdgcn_global_load_lds((const __attribute__((address_space(1))) void*)g,
                                   (__attribute__((address_space(3))) void*)l, 16, 0, 0);
}

// ---------------- convert f32 -> bf16 (8 elems/thread) ----------------
__global__ __launch_bounds__(256) void cvt_bf16_kernel(const float* __restrict__ src,
                                                       unsigned short* __restrict__ dst,
                                                       int n8) {
  int i = blockIdx.x * 256 + threadIdx.x;
  if (i >= n8) return;
  const float4* s4 = (const float4*)src + (size_t)i * 2;
  float4 f0 = s4[0], f1 = s4[1];
  short8v o;
  o[0] = (short)f2bf(f0.x); o[1] = (short)f2bf(f0.y);
  o[2] = (short)f2bf(f0.z); o[3] = (short)f2bf(f0.w);
  o[4] = (short)f2bf(f1.x); o[5] = (short)f2bf(f1.y);
  o[6] = (short)f2bf(f1.z); o[7] = (short)f2bf(f1.w);
  *(short8v*)(dst + (size_t)i * 8) = o;
}

// ---------------- transpose-convert W[K][N] f32 -> WT[N][K] bf16 ----------------
__global__ __launch_bounds__(256) void transpose_bf16_kernel(const float* __restrict__ W,
                                                             unsigned short* __restrict__ WT,
                                                             int K, int N) {
  __shared__ float tile[64][65];
  int n0 = blockIdx.x * 64, k0 = blockIdx.y * 64;
  int tid = threadIdx.x;
#pragma unroll
  for (int i = 0; i < 4; ++i) {
    int idx = i * 256 + tid;
    int r = idx >> 4, c4 = (idx & 15) * 4;
    float4 v = *(const float4*)(W + (size_t)(k0 + r) * N + n0 + c4);
    tile[r][c4] = v.x; tile[r][c4 + 1] = v.y; tile[r][c4 + 2] = v.z; tile[r][c4 + 3] = v.w;
  }
  __syncthreads();
#pragma unroll
  for (int i = 0; i < 4; ++i) {
    int idx = i * 256 + tid;
    int nr = idx >> 4, k4 = (idx & 15) * 4;
    ushort4 o;
    o.x = f2bf(tile[k4 + 0][nr]);
    o.y = f2bf(tile[k4 + 1][nr]);
    o.z = f2bf(tile[k4 + 2][nr]);
    o.w = f2bf(tile[k4 + 3][nr]);
    *(ushort4*)(WT + (size_t)(n0 + nr) * K + k0 + k4) = o;
  }
}

// ---------------- GEMM: C[M][N] = A[M][K] * BT[N][K]^T  (bf16 in, bf16/f32 out) -------
template <int BF16OUT>
__global__ __launch_bounds__(256) void gemm_bt_kernel(const unsigned short* __restrict__ A,
                                                      const unsigned short* __restrict__ BT,
                                                      void* __restrict__ Cout,
                                                      int M, int N, int K) {
  __shared__ __align__(16) char lds[32768];
  char* As = lds;
  char* Bs = lds + 16384;

  int nbn = N >> 7;
  int nwg = gridDim.x;
  int wg = blockIdx.x;
  int per = nwg >> 3;                       // nwg % 8 == 0 for our launches
  int swz = (wg & 7) * per + (wg >> 3);     // XCD-aware swizzle
  int tm = swz / nbn, tn = swz % nbn;

  int tid = threadIdx.x;
  int wid = tid >> 6, lane = tid & 63;
  int l15 = lane & 15, lhi = lane >> 4;
  int wm = wid >> 1, wn = wid & 1;

  const unsigned short* Abase = A + (size_t)(tm * 128) * K;
  const unsigned short* Bbase = BT + (size_t)(tn * 128) * K;

  // staging constants: 4 rounds, thread -> (row, slot); source pre-swizzled (rule 21)
  size_t ofs[4];
#pragma unroll
  for (int i = 0; i < 4; ++i) {
    int row = i * 32 + (tid >> 3);
    int ss = (tid & 7) ^ (row & 7);
    ofs[i] = (size_t)row * K + ss * 8;
  }

  f32x4 acc[4][4] = {};

  for (int kt = 0; kt < K; kt += 64) {
    __syncthreads();
#pragma unroll
    for (int i = 0; i < 4; ++i)
      load_lds_16B(Abase + ofs[i] + kt, As + i * 4096 + tid * 16);
#pragma unroll
    for (int i = 0; i < 4; ++i)
      load_lds_16B(Bbase + ofs[i] + kt, Bs + i * 4096 + tid * 16);
    __syncthreads();

#pragma unroll
    for (int ks = 0; ks < 2; ++ks) {
      short8v af[4], bfr[4];
#pragma unroll
      for (int mi = 0; mi < 4; ++mi) {
        int row = wm * 64 + mi * 16 + l15;
        int ss = (ks * 4 + lhi) ^ (row & 7);
        af[mi] = *(const short8v*)(As + row * 128 + ss * 16);
      }
#pragma unroll
      for (int ni = 0; ni < 4; ++ni) {
        int row = wn * 64 + ni * 16 + l15;
        int ss = (ks * 4 + lhi) ^ (row & 7);
        bfr[ni] = *(const short8v*)(Bs + row * 128 + ss * 16);
      }
#pragma unroll
      for (int mi = 0; mi < 4; ++mi)
#pragma unroll
        for (int ni = 0; ni < 4; ++ni)
          acc[mi][ni] = __builtin_amdgcn_mfma_f32_16x16x32_bf16(af[mi], bfr[ni], acc[mi][ni], 0, 0, 0);
    }
  }

#pragma unroll
  for (int mi = 0; mi < 4; ++mi)
#pragma unroll
    for (int ni = 0; ni < 4; ++ni)
#pragma unroll
      for (int r = 0; r < 4; ++r) {
        int row = tm * 128 + wm * 64 + mi * 16 + lhi * 4 + r;
        int col = tn * 128 + wn * 64 + ni * 16 + l15;
        float v = acc[mi][ni][r];
        if (BF16OUT)
          ((unsigned short*)Cout)[(size_t)row * N + col] = f2bf(v);
        else
          ((float*)Cout)[(size_t)row * N + col] = v;
      }
}

// ---------------- causal flash attention ----------------
// qkv: [B*T][3072] bf16 (q|k|v each 1024 = 16 heads x 64). y: [B*T][1024] bf16.
__global__ __launch_bounds__(256) void attn_kernel(const unsigned short* __restrict__ qkv,
                                                   unsigned short* __restrict__ yb) {
  const int T = 2048, LD = 3072;
  int qt = blockIdx.x;
  int bh = blockIdx.y;
  int b = bh >> 4, h = bh & 15;
  int q0 = qt * 64;
  int tid = threadIdx.x;
  int wid = tid >> 6, lane = tid & 63;
  int l15 = lane & 15, lhi = lane >> 4;

  __shared__ __align__(16) char Ks[8192];   // [64 kv][64 d] bf16, slot ^= kv&7
  __shared__ __align__(16) char Vt[8192];   // VT [64 d][64 kv] bf16, slot ^= d>>3
  __shared__ __align__(16) char Ps[8192];   // per-wave [16 q][64 kv] bf16, slot ^= q&7
  char* Pw = Ps + wid * 2048;

  // Q fragments, direct global->reg (A-operand layout)
  int qrow = q0 + wid * 16 + l15;
  const unsigned short* qp = qkv + (size_t)(b * T + qrow) * LD + h * 64;
  short8v qf[2];
  qf[0] = *(const short8v*)(qp + lhi * 8);
  qf[1] = *(const short8v*)(qp + 32 + lhi * 8);

  const unsigned short* kbase = qkv + (size_t)b * T * LD + 1024 + h * 64;
  const unsigned short* vbase0 = qkv + (size_t)b * T * LD + 2048 + h * 64;

  f32x4 o[4] = {};
  float mrow[4], lrow[4];
#pragma unroll
  for (int r = 0; r < 4; ++r) { mrow[r] = -1e30f; lrow[r] = 0.f; }

  int ntiles = qt + 1;
  for (int it = 0; it < ntiles; ++it) {
    int k0 = it * 64;
    __syncthreads();
    // stage K tile (global_load_lds, pre-swizzled source)
#pragma unroll
    for (int i = 0; i < 2; ++i) {
      int row = i * 32 + (tid >> 3);
      int ss = (tid & 7) ^ (row & 7);
      load_lds_16B(kbase + (size_t)(k0 + row) * LD + ss * 8, Ks + i * 4096 + tid * 16);
    }
    // stage V tile transposed via registers
    {
      int kvA = tid >> 3;
      int d0 = (tid & 7) * 8;
      const unsigned short* vp = vbase0 + (size_t)(k0 + kvA) * LD + d0;
      short8v v0 = *(const short8v*)vp;
      short8v v1 = *(const short8v*)(vp + (size_t)32 * LD);
      int kvB = kvA + 32;
#pragma unroll
      for (int j = 0; j < 8; ++j) {
        int d = d0 + j;
        int rowb = d * 128;
        *(unsigned short*)(Vt + rowb + (((kvA >> 3) ^ (d >> 3)) * 16) + (kvA & 7) * 2) = (unsigned short)v0[j];
        *(unsigned short*)(Vt + rowb + (((kvB >> 3) ^ (d >> 3)) * 16) + (kvB & 7) * 2) = (unsigned short)v1[j];
      }
    }
    __syncthreads();

    // S = Q K^T for this wave's 16 q rows
    f32x4 s[4] = {};
#pragma unroll
    for (int ks = 0; ks < 2; ++ks) {
      short8v bk[4];
#pragma unroll
      for (int ni = 0; ni < 4; ++ni) {
        int kvr = ni * 16 + l15;
        int ss = (ks * 4 + lhi) ^ (kvr & 7);
        bk[ni] = *(const short8v*)(Ks + kvr * 128 + ss * 16);
      }
#pragma unroll
      for (int ni = 0; ni < 4; ++ni)
        s[ni] = __builtin_amdgcn_mfma_f32_16x16x32_bf16(qf[ks], bk[ni], s[ni], 0, 0, 0);
    }

    bool diag = (it == ntiles - 1);
    // online softmax (wave-parallel: shfl_xor reduce over the 16-lane group)
#pragma unroll
    for (int r = 0; r < 4; ++r) {
      int q_abs = q0 + wid * 16 + lhi * 4 + r;
#pragma unroll
      for (int ni = 0; ni < 4; ++ni) {
        float sv = s[ni][r] * 0.125f;
        if (diag) {
          int kv_abs = k0 + ni * 16 + l15;
          if (kv_abs > q_abs) sv = -1e30f;
        }
        s[ni][r] = sv;
      }
      float mt = fmaxf(fmaxf(s[0][r], s[1][r]), fmaxf(s[2][r], s[3][r]));
      mt = fmaxf(mt, __shfl_xor(mt, 1));
      mt = fmaxf(mt, __shfl_xor(mt, 2));
      mt = fmaxf(mt, __shfl_xor(mt, 4));
      mt = fmaxf(mt, __shfl_xor(mt, 8));
      float mfull = fmaxf(mrow[r], mt);
      float alpha = __expf(mrow[r] - mfull);
      mrow[r] = mfull;
      float rs = 0.f;
#pragma unroll
      for (int ni = 0; ni < 4; ++ni) {
        float p = __expf(s[ni][r] - mfull);
        s[ni][r] = p;
        rs += p;
      }
      rs += __shfl_xor(rs, 1);
      rs += __shfl_xor(rs, 2);
      rs += __shfl_xor(rs, 4);
      rs += __shfl_xor(rs, 8);
      lrow[r] = lrow[r] * alpha + rs;
#pragma unroll
      for (int nd = 0; nd < 4; ++nd) o[nd][r] *= alpha;
    }

    // P (C-layout regs) -> per-wave LDS (swizzled) -> A-operand fragments
#pragma unroll
    for (int r = 0; r < 4; ++r)
#pragma unroll
      for (int ni = 0; ni < 4; ++ni) {
        int row = lhi * 4 + r;
        int col = ni * 16 + l15;
        int ss = (col >> 3) ^ (row & 7);
        *(unsigned short*)(Pw + row * 128 + ss * 16 + (col & 7) * 2) = f2bf(s[ni][r]);
      }

#pragma unroll
    for (int ks = 0; ks < 2; ++ks) {
      int ssp = (ks * 4 + lhi) ^ (l15 & 7);
      short8v pa = *(const short8v*)(Pw + l15 * 128 + ssp * 16);
#pragma unroll
      for (int nd = 0; nd < 4; ++nd) {
        int d = nd * 16 + l15;
        int ss = (ks * 4 + lhi) ^ (d >> 3);
        short8v bv = *(const short8v*)(Vt + d * 128 + ss * 16);
        o[nd] = __builtin_amdgcn_mfma_f32_16x16x32_bf16(pa, bv, o[nd], 0, 0, 0);
      }
    }
  }

  // epilogue: normalize and store y bf16
#pragma unroll
  for (int nd = 0; nd < 4; ++nd)
#pragma unroll
    for (int r = 0; r < 4; ++r) {
      int qa = q0 + wid * 16 + lhi * 4 + r;
      float val = o[nd][r] / lrow[r];
      yb[(size_t)(b * T + qa) * 1024 + h * 64 + nd * 16 + l15] = f2bf(val);
    }
}

// ---------------- launcher ----------------
extern "C" void kernel_launch(void* const* d_in, const int* in_sizes, int n_in,
                              void* d_out, int out_size, void* d_ws, size_t ws_size,
                              hipStream_t stream) {
  const float* x = (const float*)d_in[0];     // [2,2048,1024]
  const float* Wa = (const float*)d_in[1];    // [1024,3072]
  const float* Wp = (const float*)d_in[2];    // [1024,1024]
  float* out = (float*)d_out;                 // [2,2048,1024] f32

  char* ws = (char*)d_ws;
  unsigned short* xb  = (unsigned short*)(ws);                      // 8 MB  [4096][1024]
  unsigned short* WaT = (unsigned short*)(ws + (size_t)(8u  << 20)); // 6 MB  [3072][1024]
  unsigned short* WpT = (unsigned short*)(ws + (size_t)(14u << 20)); // 2 MB  [1024][1024]
  unsigned short* qkv = (unsigned short*)(ws + (size_t)(16u << 20)); // 24 MB [4096][3072]
  unsigned short* yb  = (unsigned short*)(ws + (size_t)(40u << 20)); // 8 MB  [4096][1024]

  cvt_bf16_kernel<<<2048, 256, 0, stream>>>(x, xb, 524288);
  transpose_bf16_kernel<<<dim3(48, 16), 256, 0, stream>>>(Wa, WaT, 1024, 3072);
  transpose_bf16_kernel<<<dim3(16, 16), 256, 0, stream>>>(Wp, WpT, 1024, 1024);
  gemm_bt_kernel<1><<<dim3(768), 256, 0, stream>>>(xb, WaT, qkv, 4096, 3072, 1024);
  attn_kernel<<<dim3(32, 32), 256, 0, stream>>>(qkv, yb);
  gemm_bt_kernel<0><<<dim3(256), 256, 0, stream>>>(yb, WpT, out, 4096, 1024, 1024);
}

// Round 2
// 140.812 us; speedup vs baseline: 1.5253x; 1.5253x over previous
//
#include <hip/hip_runtime.h>
#include <cstdint>
#include <cstddef>

typedef __attribute__((ext_vector_type(8))) short short8v;
typedef __attribute__((ext_vector_type(4))) float f32x4;
typedef __attribute__((ext_vector_type(4))) unsigned short ushort4v;

__device__ __forceinline__ unsigned short f2bf(float f) {
  union { float f; uint32_t u; } v; v.f = f;
  uint32_t u = v.u;
  return (unsigned short)((u + 0x7fffu + ((u >> 16) & 1u)) >> 16);
}

__device__ __forceinline__ void load_lds_16B(const void* g, void* l) {
  __builtin_amdgcn_global_load_lds((const __attribute__((address_space(1))) void*)g,
                                   (__attribute__((address_space(3))) void*)l, 16, 0, 0);
}

// ---------------- convert f32 -> bf16 (8 elems/thread) ----------------
__global__ __launch_bounds__(256) void cvt_bf16_kernel(const float* __restrict__ src,
                                                       unsigned short* __restrict__ dst,
                                                       int n8) {
  int i = blockIdx.x * 256 + threadIdx.x;
  if (i >= n8) return;
  const float4* s4 = (const float4*)src + (size_t)i * 2;
  float4 f0 = s4[0], f1 = s4[1];
  short8v o;
  o[0] = (short)f2bf(f0.x); o[1] = (short)f2bf(f0.y);
  o[2] = (short)f2bf(f0.z); o[3] = (short)f2bf(f0.w);
  o[4] = (short)f2bf(f1.x); o[5] = (short)f2bf(f1.y);
  o[6] = (short)f2bf(f1.z); o[7] = (short)f2bf(f1.w);
  *(short8v*)(dst + (size_t)i * 8) = o;
}

// ---------------- transpose-convert W[K][N] f32 -> WT[N][K] bf16 ----------------
__global__ __launch_bounds__(256) void transpose_bf16_kernel(const float* __restrict__ W,
                                                             unsigned short* __restrict__ WT,
                                                             int K, int N) {
  __shared__ float tile[64][65];
  int n0 = blockIdx.x * 64, k0 = blockIdx.y * 64;
  int tid = threadIdx.x;
#pragma unroll
  for (int i = 0; i < 4; ++i) {
    int idx = i * 256 + tid;
    int r = idx >> 4, c4 = (idx & 15) * 4;
    float4 v = *(const float4*)(W + (size_t)(k0 + r) * N + n0 + c4);
    tile[r][c4] = v.x; tile[r][c4 + 1] = v.y; tile[r][c4 + 2] = v.z; tile[r][c4 + 3] = v.w;
  }
  __syncthreads();
#pragma unroll
  for (int i = 0; i < 4; ++i) {
    int idx = i * 256 + tid;
    int nr = idx >> 4, k4 = (idx & 15) * 4;
    ushort4 o;
    o.x = f2bf(tile[k4 + 0][nr]);
    o.y = f2bf(tile[k4 + 1][nr]);
    o.z = f2bf(tile[k4 + 2][nr]);
    o.w = f2bf(tile[k4 + 3][nr]);
    *(ushort4*)(WT + (size_t)(n0 + nr) * K + k0 + k4) = o;
  }
}

// ---------------- GEMM: C[M][N] = A[M][K] * BT[N][K]^T  (bf16 in, bf16/f32 out) -------
template <int BF16OUT>
__global__ __launch_bounds__(256) void gemm_bt_kernel(const unsigned short* __restrict__ A,
                                                      const unsigned short* __restrict__ BT,
                                                      void* __restrict__ Cout,
                                                      int M, int N, int K) {
  __shared__ __align__(16) char lds[32768];
  char* As = lds;
  char* Bs = lds + 16384;

  int nbn = N >> 7;
  int nwg = gridDim.x;
  int wg = blockIdx.x;
  int per = nwg >> 3;
  int swz = (wg & 7) * per + (wg >> 3);     // XCD-aware swizzle (nwg % 8 == 0)
  int tm = swz / nbn, tn = swz % nbn;

  int tid = threadIdx.x;
  int wid = tid >> 6, lane = tid & 63;
  int l15 = lane & 15, lhi = lane >> 4;
  int wm = wid >> 1, wn = wid & 1;

  const unsigned short* Abase = A + (size_t)(tm * 128) * K;
  const unsigned short* Bbase = BT + (size_t)(tn * 128) * K;

  size_t ofs[4];
#pragma unroll
  for (int i = 0; i < 4; ++i) {
    int row = i * 32 + (tid >> 3);
    int ss = (tid & 7) ^ (row & 7);
    ofs[i] = (size_t)row * K + ss * 8;
  }

  f32x4 acc[4][4] = {};

  for (int kt = 0; kt < K; kt += 64) {
    __syncthreads();
#pragma unroll
    for (int i = 0; i < 4; ++i)
      load_lds_16B(Abase + ofs[i] + kt, As + i * 4096 + tid * 16);
#pragma unroll
    for (int i = 0; i < 4; ++i)
      load_lds_16B(Bbase + ofs[i] + kt, Bs + i * 4096 + tid * 16);
    __syncthreads();

#pragma unroll
    for (int ks = 0; ks < 2; ++ks) {
      short8v af[4], bfr[4];
#pragma unroll
      for (int mi = 0; mi < 4; ++mi) {
        int row = wm * 64 + mi * 16 + l15;
        int ss = (ks * 4 + lhi) ^ (row & 7);
        af[mi] = *(const short8v*)(As + row * 128 + ss * 16);
      }
#pragma unroll
      for (int ni = 0; ni < 4; ++ni) {
        int row = wn * 64 + ni * 16 + l15;
        int ss = (ks * 4 + lhi) ^ (row & 7);
        bfr[ni] = *(const short8v*)(Bs + row * 128 + ss * 16);
      }
#pragma unroll
      for (int mi = 0; mi < 4; ++mi)
#pragma unroll
        for (int ni = 0; ni < 4; ++ni)
          acc[mi][ni] = __builtin_amdgcn_mfma_f32_16x16x32_bf16(af[mi], bfr[ni], acc[mi][ni], 0, 0, 0);
    }
  }

#pragma unroll
  for (int mi = 0; mi < 4; ++mi)
#pragma unroll
    for (int ni = 0; ni < 4; ++ni)
#pragma unroll
      for (int r = 0; r < 4; ++r) {
        int row = tm * 128 + wm * 64 + mi * 16 + lhi * 4 + r;
        int col = tn * 128 + wn * 64 + ni * 16 + l15;
        float v = acc[mi][ni][r];
        if (BF16OUT)
          ((unsigned short*)Cout)[(size_t)row * N + col] = f2bf(v);
        else
          ((float*)Cout)[(size_t)row * N + col] = v;
      }
}

// ---------------- causal flash attention v2 ----------------
// Block processes q-tile PAIR (j, 31-j): constant 33 tile-units, 528 MFMA per block.
// S^T = mfma(K,Q) so softmax is lane-local; 2-phase K/V prefetch pipeline.

__device__ __forceinline__ void softmax_step(f32x4 s[4], float& m, float& l, f32x4 o[4],
                                             int q_abs, bool diag, int k0, int lhi) {
  float pm = -1e30f;
#pragma unroll
  for (int ni = 0; ni < 4; ++ni)
#pragma unroll
    for (int r = 0; r < 4; ++r) {
      float sv = s[ni][r] * 0.125f;
      if (diag) {
        int kv = k0 + ni * 16 + lhi * 4 + r;
        if (kv > q_abs) sv = -1e30f;
      }
      s[ni][r] = sv;
      pm = fmaxf(pm, sv);
    }
  pm = fmaxf(pm, __shfl_xor(pm, 16));
  pm = fmaxf(pm, __shfl_xor(pm, 32));
  float mn = fmaxf(m, pm);
  float alpha = __expf(m - mn);
  m = mn;
  float rs = 0.f;
#pragma unroll
  for (int ni = 0; ni < 4; ++ni)
#pragma unroll
    for (int r = 0; r < 4; ++r) {
      float p = __expf(s[ni][r] - mn);
      s[ni][r] = p;
      rs += p;
    }
  rs += __shfl_xor(rs, 16);
  rs += __shfl_xor(rs, 32);
  l = l * alpha + rs;
#pragma unroll
  for (int r = 0; r < 4; ++r) {
    float ar = __shfl(alpha, lhi * 4 + r);
#pragma unroll
    for (int nd = 0; nd < 4; ++nd) o[nd][r] *= ar;
  }
}

__device__ __forceinline__ void storeP(char* Pw, const f32x4 s[4], int l15, int lhi) {
#pragma unroll
  for (int ni = 0; ni < 4; ++ni) {
    ushort4v w;
#pragma unroll
    for (int r = 0; r < 4; ++r) w[r] = f2bf(s[ni][r]);
    int col0 = ni * 16 + lhi * 4;
    int sl = (col0 >> 3) ^ (l15 & 7);
    *(ushort4v*)(Pw + l15 * 128 + sl * 16 + (col0 & 7) * 2) = w;
  }
}

__global__ __launch_bounds__(256) void attn_kernel(const unsigned short* __restrict__ qkv,
                                                   unsigned short* __restrict__ yb) {
  const int T = 2048, LD = 3072;
  int bid = blockIdx.x;                 // 512 blocks
  int xcd = bid & 7, ii = bid >> 3;     // co-locate each bh's blocks on one XCD
  int bh = xcd * 4 + (ii & 3);
  int j = ii >> 2;                      // 0..15
  int b = bh >> 4, h = bh & 15;
  int qtA = j, qtB = 31 - j;

  int tid = threadIdx.x;
  int wid = tid >> 6, lane = tid & 63;
  int l15 = lane & 15, lhi = lane >> 4;

  __shared__ __align__(16) char Ks[2][8192];   // [64 kv][64 d] bf16, slot^=(kv&7)
  __shared__ __align__(16) char Vt[2][8192];   // [64 d][64 kv] bf16, slot^=(d&7)
  __shared__ __align__(16) char Ps[16384];     // per-wave 2KB x (B,A)
  char* PwB = Ps + wid * 2048;
  char* PwA = Ps + 8192 + wid * 2048;

  // Q fragments (also serve as MFMA B-operand for S^T)
  int qrowA = qtA * 64 + wid * 16 + l15;
  int qrowB = qtB * 64 + wid * 16 + l15;
  const unsigned short* qpA = qkv + (size_t)(b * T + qrowA) * LD + h * 64;
  const unsigned short* qpB = qkv + (size_t)(b * T + qrowB) * LD + h * 64;
  short8v qfA[2], qfB[2];
  qfA[0] = *(const short8v*)(qpA + lhi * 8);
  qfA[1] = *(const short8v*)(qpA + 32 + lhi * 8);
  qfB[0] = *(const short8v*)(qpB + lhi * 8);
  qfB[1] = *(const short8v*)(qpB + 32 + lhi * 8);

  const unsigned short* kbase = qkv + (size_t)b * T * LD + 1024 + h * 64;
  const unsigned short* vbase = qkv + (size_t)b * T * LD + 2048 + h * 64;

  // V staging geometry: thread -> 4 kv x 4 d
  int kv0 = (tid >> 4) * 4;
  int d0 = (tid & 15) * 4;

  f32x4 oA[4] = {}, oB[4] = {};
  float mA = -1e30f, lA = 0.f, mB = -1e30f, lB = 0.f;
  int q_absA = qtA * 64 + wid * 16 + l15;
  int q_absB = qtB * 64 + wid * 16 + l15;

  int ntB = qtB + 1;  // 32 - j tiles

  // ---- prologue: stage tile 0 into buffer 0 ----
  {
#pragma unroll
    for (int i2 = 0; i2 < 2; ++i2) {
      int row = i2 * 32 + (tid >> 3);
      int ss = (tid & 7) ^ (row & 7);
      load_lds_16B(kbase + (size_t)row * LD + ss * 8, Ks[0] + i2 * 4096 + tid * 16);
    }
    const unsigned short* vp = vbase + (size_t)kv0 * LD + d0;
    ushort4v vr0 = *(const ushort4v*)(vp);
    ushort4v vr1 = *(const ushort4v*)(vp + LD);
    ushort4v vr2 = *(const ushort4v*)(vp + 2 * LD);
    ushort4v vr3 = *(const ushort4v*)(vp + 3 * LD);
#pragma unroll
    for (int jj = 0; jj < 4; ++jj) {
      int d = d0 + jj;
      ushort4v w;
      w[0] = vr0[jj]; w[1] = vr1[jj]; w[2] = vr2[jj]; w[3] = vr3[jj];
      *(ushort4v*)(Vt[0] + d * 128 + (((kv0 >> 3) ^ (d & 7)) * 16) + (kv0 & 7) * 2) = w;
    }
  }
  __syncthreads();

  for (int it = 0; it < ntB; ++it) {
    char* KsC = Ks[it & 1];
    char* VtC = Vt[it & 1];
    char* KsN = Ks[(it + 1) & 1];
    char* VtN = Vt[(it + 1) & 1];
    int k0 = it * 64;
    bool pref = (it + 1 < ntB);
    bool doA = (it <= qtA);

    ushort4v vr0, vr1, vr2, vr3;
    if (pref) {
      int k0n = k0 + 64;
#pragma unroll
      for (int i2 = 0; i2 < 2; ++i2) {
        int row = i2 * 32 + (tid >> 3);
        int ss = (tid & 7) ^ (row & 7);
        load_lds_16B(kbase + (size_t)(k0n + row) * LD + ss * 8, KsN + i2 * 4096 + tid * 16);
      }
      const unsigned short* vp = vbase + (size_t)(k0n + kv0) * LD + d0;
      vr0 = *(const ushort4v*)(vp);
      vr1 = *(const ushort4v*)(vp + LD);
      vr2 = *(const ushort4v*)(vp + 2 * LD);
      vr3 = *(const ushort4v*)(vp + 3 * LD);
    }

    // ---- S^T = K * Q^T (shared K fragments for both q-tiles) ----
    f32x4 sB[4] = {}, sA[4] = {};
#pragma unroll
    for (int ks = 0; ks < 2; ++ks)
#pragma unroll
      for (int ni = 0; ni < 4; ++ni) {
        int row = ni * 16 + l15;
        int sl = (ks * 4 + lhi) ^ (row & 7);
        short8v kf = *(const short8v*)(KsC + row * 128 + sl * 16);
        sB[ni] = __builtin_amdgcn_mfma_f32_16x16x32_bf16(kf, qfB[ks], sB[ni], 0, 0, 0);
        if (doA) sA[ni] = __builtin_amdgcn_mfma_f32_16x16x32_bf16(kf, qfA[ks], sA[ni], 0, 0, 0);
      }

    softmax_step(sB, mB, lB, oB, q_absB, it == qtB, k0, lhi);
    if (doA) softmax_step(sA, mA, lA, oA, q_absA, it == qtA, k0, lhi);

    storeP(PwB, sB, l15, lhi);
    if (doA) storeP(PwA, sA, l15, lhi);

    // ---- PV (shared V fragments) ----
#pragma unroll
    for (int ks = 0; ks < 2; ++ks) {
      int slp = (ks * 4 + lhi) ^ (l15 & 7);
      short8v paB = *(const short8v*)(PwB + l15 * 128 + slp * 16);
      short8v paA = paB;
      if (doA) paA = *(const short8v*)(PwA + l15 * 128 + slp * 16);
#pragma unroll
      for (int nd = 0; nd < 4; ++nd) {
        int d = nd * 16 + l15;
        int slv = (ks * 4 + lhi) ^ (d & 7);
        short8v bv = *(const short8v*)(VtC + d * 128 + slv * 16);
        oB[nd] = __builtin_amdgcn_mfma_f32_16x16x32_bf16(paB, bv, oB[nd], 0, 0, 0);
        if (doA) oA[nd] = __builtin_amdgcn_mfma_f32_16x16x32_bf16(paA, bv, oA[nd], 0, 0, 0);
      }
    }

    if (pref) {
#pragma unroll
      for (int jj = 0; jj < 4; ++jj) {
        int d = d0 + jj;
        ushort4v w;
        w[0] = vr0[jj]; w[1] = vr1[jj]; w[2] = vr2[jj]; w[3] = vr3[jj];
        *(ushort4v*)(VtN + d * 128 + (((kv0 >> 3) ^ (d & 7)) * 16) + (kv0 & 7) * 2) = w;
      }
    }
    __syncthreads();
  }

  // ---- epilogue: normalize + store both q-tiles ----
#pragma unroll
  for (int r = 0; r < 4; ++r) {
    float lrB = __shfl(lB, lhi * 4 + r);
    float lrA = __shfl(lA, lhi * 4 + r);
    float invB = 1.0f / lrB;
    float invA = 1.0f / lrA;
    int qB = qtB * 64 + wid * 16 + lhi * 4 + r;
    int qA = qtA * 64 + wid * 16 + lhi * 4 + r;
#pragma unroll
    for (int nd = 0; nd < 4; ++nd) {
      yb[(size_t)(b * T + qB) * 1024 + h * 64 + nd * 16 + l15] = f2bf(oB[nd][r] * invB);
      yb[(size_t)(b * T + qA) * 1024 + h * 64 + nd * 16 + l15] = f2bf(oA[nd][r] * invA);
    }
  }
}

// ---------------- launcher ----------------
extern "C" void kernel_launch(void* const* d_in, const int* in_sizes, int n_in,
                              void* d_out, int out_size, void* d_ws, size_t ws_size,
                              hipStream_t stream) {
  const float* x = (const float*)d_in[0];     // [2,2048,1024]
  const float* Wa = (const float*)d_in[1];    // [1024,3072]
  const float* Wp = (const float*)d_in[2];    // [1024,1024]
  float* out = (float*)d_out;                 // [2,2048,1024] f32

  char* ws = (char*)d_ws;
  unsigned short* xb  = (unsigned short*)(ws);                       // 8 MB  [4096][1024]
  unsigned short* WaT = (unsigned short*)(ws + (size_t)(8u  << 20)); // 6 MB  [3072][1024]
  unsigned short* WpT = (unsigned short*)(ws + (size_t)(14u << 20)); // 2 MB  [1024][1024]
  unsigned short* qkv = (unsigned short*)(ws + (size_t)(16u << 20)); // 24 MB [4096][3072]
  unsigned short* yb  = (unsigned short*)(ws + (size_t)(40u << 20)); // 8 MB  [4096][1024]

  cvt_bf16_kernel<<<2048, 256, 0, stream>>>(x, xb, 524288);
  transpose_bf16_kernel<<<dim3(48, 16), 256, 0, stream>>>(Wa, WaT, 1024, 3072);
  transpose_bf16_kernel<<<dim3(16, 16), 256, 0, stream>>>(Wp, WpT, 1024, 1024);
  gemm_bt_kernel<1><<<dim3(768), 256, 0, stream>>>(xb, WaT, qkv, 4096, 3072, 1024);
  attn_kernel<<<dim3(512), 256, 0, stream>>>(qkv, yb);
  gemm_bt_kernel<0><<<dim3(256), 256, 0, stream>>>(yb, WpT, out, 4096, 1024, 1024);
}